// Round 1
// baseline (534.024 us; speedup 1.0000x reference)
//
#include <hip/hip_runtime.h>

// Problem constants
constexpr int TT = 5;     // temporal length
constexpr int KK = 25;    // spatial neighbors
constexpr int CC = 256;   // channels
#define NEGV -1e10f

// ---------------------------------------------------------------------------
// Tiled f32 GEMM:  C[M x 256] = A[M x 256 (row stride lda)] @ W[256 x 256] + bias
// grid = (ceil(M/64), 4), block = 256 threads, each thread computes 4x4.
// LDS layout is k-major; A-fragment reads are 16-lane broadcasts (no conflict),
// B-fragment reads are 2-way (free on CDNA4).
// ---------------------------------------------------------------------------
__global__ __launch_bounds__(256) void gemm256(
    const float* __restrict__ A, int lda, int M,
    const float* __restrict__ W, const float* __restrict__ bias,
    float* __restrict__ C)
{
    __shared__ float sA[16][68];   // [k][m], padded row (272B, 16B-aligned)
    __shared__ float sB[16][64];   // [k][n]

    const int bm  = blockIdx.x * 64;
    const int bn  = blockIdx.y * 64;
    const int tid = threadIdx.x;
    const int tm  = tid >> 4;      // 0..15 -> row group (4 rows)
    const int tn  = tid & 15;      // 0..15 -> col group (4 cols)

    // staging assignments
    const int r  = tid >> 2;         // 0..63 : A row within tile
    const int cA = (tid & 3) << 2;   // 0,4,8,12 : A k-offset (float4)
    const int kB = tid >> 4;         // 0..15 : B k row
    const int jB = (tid & 15) << 2;  // 0..60 : B col offset (float4)

    float acc[4][4] = {};

    for (int k0 = 0; k0 < 256; k0 += 16) {
        float4 a4 = make_float4(0.f, 0.f, 0.f, 0.f);
        if (bm + r < M)
            a4 = *(const float4*)(A + (size_t)(bm + r) * lda + k0 + cA);
        float4 b4 = *(const float4*)(W + (size_t)(k0 + kB) * 256 + bn + jB);

        __syncthreads();   // previous iteration's LDS reads complete
        sA[cA + 0][r] = a4.x;
        sA[cA + 1][r] = a4.y;
        sA[cA + 2][r] = a4.z;
        sA[cA + 3][r] = a4.w;
        *(float4*)(&sB[kB][jB]) = b4;
        __syncthreads();

        #pragma unroll
        for (int k = 0; k < 16; ++k) {
            float4 a = *(const float4*)(&sA[k][tm * 4]);
            float4 b = *(const float4*)(&sB[k][tn * 4]);
            acc[0][0] += a.x * b.x; acc[0][1] += a.x * b.y; acc[0][2] += a.x * b.z; acc[0][3] += a.x * b.w;
            acc[1][0] += a.y * b.x; acc[1][1] += a.y * b.y; acc[1][2] += a.y * b.z; acc[1][3] += a.y * b.w;
            acc[2][0] += a.z * b.x; acc[2][1] += a.z * b.y; acc[2][2] += a.z * b.z; acc[2][3] += a.z * b.w;
            acc[3][0] += a.w * b.x; acc[3][1] += a.w * b.y; acc[3][2] += a.w * b.z; acc[3][3] += a.w * b.w;
        }
    }

    const float4 bias4 = *(const float4*)(bias + bn + tn * 4);
    #pragma unroll
    for (int i = 0; i < 4; ++i) {
        const int row = bm + tm * 4 + i;
        if (row < M) {
            float4 o;
            o.x = acc[i][0] + bias4.x;
            o.y = acc[i][1] + bias4.y;
            o.z = acc[i][2] + bias4.z;
            o.w = acc[i][3] + bias4.w;
            *(float4*)(C + (size_t)row * 256 + bn + tn * 4) = o;
        }
    }
}

// ---------------------------------------------------------------------------
// Temporal attention: one block (256 thr) per node. thread = h*32 + d.
// q [N,256], k/v [N,T,256], tmask [N,T] -> ctx [N,256]
// ---------------------------------------------------------------------------
__global__ __launch_bounds__(256) void attn_t(
    const float* __restrict__ q, const float* __restrict__ k,
    const float* __restrict__ v, const int* __restrict__ tmask,
    float* __restrict__ ctx)
{
    const int n   = blockIdx.x;
    const int tid = threadIdx.x;
    const float scale = 0.1767766952966369f;  // 1/sqrt(32)

    const float qv = q[(size_t)n * 256 + tid];
    float s[TT];
    #pragma unroll
    for (int t = 0; t < TT; ++t) {
        float p = qv * k[((size_t)n * TT + t) * 256 + tid];
        p += __shfl_xor(p, 16);
        p += __shfl_xor(p, 8);
        p += __shfl_xor(p, 4);
        p += __shfl_xor(p, 2);
        p += __shfl_xor(p, 1);
        s[t] = (tmask[n * TT + t] == 0) ? NEGV : p * scale;
    }
    float m = s[0];
    #pragma unroll
    for (int t = 1; t < TT; ++t) m = fmaxf(m, s[t]);
    float l = 0.f, p[TT];
    #pragma unroll
    for (int t = 0; t < TT; ++t) { p[t] = expf(s[t] - m); l += p[t]; }
    const float inv = 1.0f / l;
    float acc = 0.f;
    #pragma unroll
    for (int t = 0; t < TT; ++t)
        acc += p[t] * v[((size_t)n * TT + t) * 256 + tid];
    ctx[(size_t)n * 256 + tid] = acc * inv;
}

// ---------------------------------------------------------------------------
// Spatial attention: one block (256 thr) per node. thread = h*32 + d.
// sq [N,256], k1/v1 [N,256], nbrs [N,25], smask [N,25] -> sctx [N,256]
// ---------------------------------------------------------------------------
__global__ __launch_bounds__(256) void attn_s(
    const float* __restrict__ sq, const float* __restrict__ k1,
    const float* __restrict__ v1, const int* __restrict__ nbrs,
    const int* __restrict__ smask, float* __restrict__ sctx)
{
    const int n   = blockIdx.x;
    const int tid = threadIdx.x;
    const float scale = 0.1767766952966369f;

    __shared__ int nb[KK];
    __shared__ int mk[KK];
    if (tid < KK) {
        nb[tid] = nbrs[n * KK + tid];
        mk[tid] = smask[n * KK + tid];
    }
    __syncthreads();

    const float qv = sq[(size_t)n * 256 + tid];
    float s[KK];
    #pragma unroll
    for (int j = 0; j < KK; ++j) {
        float p = qv * k1[(size_t)nb[j] * 256 + tid];
        p += __shfl_xor(p, 16);
        p += __shfl_xor(p, 8);
        p += __shfl_xor(p, 4);
        p += __shfl_xor(p, 2);
        p += __shfl_xor(p, 1);
        s[j] = (mk[j] == 0) ? NEGV : p * scale;
    }
    float m = s[0];
    #pragma unroll
    for (int j = 1; j < KK; ++j) m = fmaxf(m, s[j]);
    float l = 0.f;
    #pragma unroll
    for (int j = 0; j < KK; ++j) { s[j] = expf(s[j] - m); l += s[j]; }
    const float inv = 1.0f / l;
    float acc = 0.f;
    #pragma unroll
    for (int j = 0; j < KK; ++j)
        acc += s[j] * v1[(size_t)nb[j] * 256 + tid];
    sctx[(size_t)n * 256 + tid] = acc * inv;
}

// ---------------------------------------------------------------------------
extern "C" void kernel_launch(void* const* d_in, const int* in_sizes, int n_in,
                              void* d_out, int out_size, void* d_ws, size_t ws_size,
                              hipStream_t stream)
{
    const float* x   = (const float*)d_in[0];
    const float* tWq = (const float*)d_in[1];
    const float* tbq = (const float*)d_in[2];
    const float* tWk = (const float*)d_in[3];
    const float* tbk = (const float*)d_in[4];
    const float* tWv = (const float*)d_in[5];
    const float* tbv = (const float*)d_in[6];
    const float* tWo = (const float*)d_in[7];
    const float* tbo = (const float*)d_in[8];
    const float* sWq = (const float*)d_in[9];
    const float* sbq = (const float*)d_in[10];
    const float* sWk = (const float*)d_in[11];
    const float* sbk = (const float*)d_in[12];
    const float* sWv = (const float*)d_in[13];
    const float* sbv = (const float*)d_in[14];
    const float* sWo = (const float*)d_in[15];
    const float* sbo = (const float*)d_in[16];
    const int* nbrs  = (const int*)d_in[17];
    const int* tmask = (const int*)d_in[18];
    const int* smask = (const int*)d_in[19];
    float* out = (float*)d_out;

    const int N  = in_sizes[0] / (TT * CC);   // 10000
    const int MT = N * TT;                    // 50000

    // workspace layout (floats); aggressive reuse keeps it at ~133 MB
    float* ws   = (float*)d_ws;
    float* kbuf = ws;                                  // [N*T*256]
    float* vbuf = kbuf + (size_t)MT * CC;              // [N*T*256]
    float* qbuf = vbuf + (size_t)MT * CC;              // [N*256]
    float* ctx  = qbuf + (size_t)N * CC;               // [N*256]
    float* ht   = ctx + (size_t)N * CC;                // [N*256]
    float* sqb  = qbuf;               // q dead after attn_t
    float* k1   = kbuf;               // k dead after attn_t
    float* v1   = kbuf + (size_t)N * CC;
    float* sctx = ctx;                // ctx dead after h_t projection

    dim3 blk(256);
    dim3 gkv((MT + 63) / 64, 4);
    dim3 g1((N + 63) / 64, 4);

    // temporal projections
    gemm256<<<gkv, blk, 0, stream>>>(x, 256, MT, tWk, tbk, kbuf);
    gemm256<<<gkv, blk, 0, stream>>>(x, 256, MT, tWv, tbv, vbuf);
    gemm256<<<g1, blk, 0, stream>>>(x + (TT - 1) * CC, TT * CC, N, tWq, tbq, qbuf);
    // temporal attention
    attn_t<<<N, blk, 0, stream>>>(qbuf, kbuf, vbuf, tmask, ctx);
    // h_t
    gemm256<<<g1, blk, 0, stream>>>(ctx, 256, N, tWo, tbo, ht);
    // spatial projections
    gemm256<<<g1, blk, 0, stream>>>(ht, 256, N, sWq, sbq, sqb);
    gemm256<<<g1, blk, 0, stream>>>(ht, 256, N, sWk, sbk, k1);
    gemm256<<<g1, blk, 0, stream>>>(ht, 256, N, sWv, sbv, v1);
    // spatial attention
    attn_s<<<N, blk, 0, stream>>>(sqb, k1, v1, nbrs, smask, sctx);
    // output projection
    gemm256<<<g1, blk, 0, stream>>>(sctx, 256, N, sWo, sbo, out);
}

// Round 2
// 447.686 us; speedup vs baseline: 1.1929x; 1.1929x over previous
//
#include <hip/hip_runtime.h>

constexpr int TT = 5;     // temporal length
constexpr int KK = 25;    // spatial neighbors
#define NEGV -1e10f

typedef __attribute__((ext_vector_type(8))) short s16x8;
typedef __attribute__((ext_vector_type(8))) unsigned short u16x8;
typedef __attribute__((ext_vector_type(4))) float f32x4;

__device__ __forceinline__ unsigned short f2bf(float f) {
    union { float f; unsigned u; } v; v.f = f;
    unsigned r = v.u + 0x7fffu + ((v.u >> 16) & 1u);
    return (unsigned short)(r >> 16);
}
__device__ __forceinline__ float bf2f(unsigned short b) {
    union { unsigned u; float f; } v; v.u = ((unsigned)b) << 16;
    return v.f;
}

// ---------------------------------------------------------------------------
// Weight prep: W [256k x 256n] f32  ->  Wt_hi/Wt_lo [n][k] bf16 (split),
// plus bias copy into concatenated bias buffer. grid(4,4), block 256.
// ---------------------------------------------------------------------------
__global__ __launch_bounds__(256) void prep_w(
    const float* __restrict__ W, const float* __restrict__ b,
    unsigned short* __restrict__ wh, unsigned short* __restrict__ wl,
    float* __restrict__ bc)
{
    __shared__ float sT[64][65];
    const int t  = threadIdx.x;
    const int k0 = blockIdx.x * 64, n0 = blockIdx.y * 64;
    const int kk = t >> 2;
    #pragma unroll
    for (int c = 0; c < 4; ++c) {
        const int col = (t & 3) * 16 + c * 4;
        float4 v = *(const float4*)(W + (size_t)(k0 + kk) * 256 + n0 + col);
        sT[kk][col] = v.x; sT[kk][col + 1] = v.y; sT[kk][col + 2] = v.z; sT[kk][col + 3] = v.w;
    }
    __syncthreads();
    const int n = t >> 2, ks = (t & 3) * 16;
    u16x8 vh[2], vl[2];
    #pragma unroll
    for (int j = 0; j < 16; ++j) {
        float f = sT[ks + j][n];
        unsigned short h = f2bf(f);
        vh[j >> 3][j & 7] = h;
        vl[j >> 3][j & 7] = f2bf(f - bf2f(h));
    }
    unsigned short* ph = wh + (size_t)(n0 + n) * 256 + k0 + ks;
    unsigned short* pl = wl + (size_t)(n0 + n) * 256 + k0 + ks;
    *(u16x8*)(ph)     = vh[0];
    *(u16x8*)(ph + 8) = vh[1];
    *(u16x8*)(pl)     = vl[0];
    *(u16x8*)(pl + 8) = vl[1];
    if (blockIdx.x == 0 && blockIdx.y == 0) bc[t] = b[t];
}

// ---------------------------------------------------------------------------
// Split-bf16 MFMA GEMM: C[M x Ntot] = A[M x K=256 (stride lda)] @ W + bias
// W pre-transposed/split: Wh/Wl [Ntot][256] bf16. 512 threads = 8 waves (2x4),
// tile BM x 256, BK=32, MFMA 16x16x32. A converted f32->hi/lo bf16 in-register
// during LDS staging (padded rows: 40 elems = 80B -> 2-way bank alias, free).
// B fragments read directly from global (L2-resident panels).
// ---------------------------------------------------------------------------
template<int BM>
__global__ __launch_bounds__(512) void gemm_mfma(
    const float* A, int lda, int M,
    const unsigned short* __restrict__ Wh, const unsigned short* __restrict__ Wl,
    const float* __restrict__ bias,
    float* C, int ldc)
{
    constexpr int BK  = 32;
    constexpr int PAD = 40;
    constexpr int WM  = BM / 2;
    constexpr int MF  = WM / 16;
    constexpr int EPT = BM * BK / 512;   // A elems per thread per k-step

    __shared__ unsigned short sAh[BM][PAD];
    __shared__ unsigned short sAl[BM][PAD];

    const int tid = threadIdx.x;
    const int l   = tid & 63;
    const int wid = tid >> 6;
    const int mw  = wid >> 2, nw = wid & 3;
    const int bm  = blockIdx.x * BM;
    const int bn  = blockIdx.y * 256;
    const int l15 = l & 15, l4 = l >> 4;

    const int srow = (BM == 128) ? (tid >> 2) : (tid >> 3);
    const int skof = (BM == 128) ? ((tid & 3) * 8) : ((tid & 7) * 4);
    const int grow = bm + srow;

    f32x4 acc[MF][4];
    #pragma unroll
    for (int i = 0; i < MF; ++i)
        #pragma unroll
        for (int j = 0; j < 4; ++j) acc[i][j] = f32x4{0.f, 0.f, 0.f, 0.f};

    for (int k0 = 0; k0 < 256; k0 += BK) {
        // ---- load + convert A slice ----
        float av[EPT];
        if (grow < M) {
            #pragma unroll
            for (int c = 0; c < EPT; c += 4) {
                float4 t = *(const float4*)(A + (size_t)grow * lda + k0 + skof + c);
                av[c] = t.x; av[c + 1] = t.y; av[c + 2] = t.z; av[c + 3] = t.w;
            }
        } else {
            #pragma unroll
            for (int c = 0; c < EPT; ++c) av[c] = 0.f;
        }
        unsigned short hi[EPT], lo[EPT];
        #pragma unroll
        for (int c = 0; c < EPT; ++c) {
            hi[c] = f2bf(av[c]);
            lo[c] = f2bf(av[c] - bf2f(hi[c]));
        }

        __syncthreads();   // previous iteration's LDS reads done
        if constexpr (EPT == 8) {
            u16x8 vh, vl;
            #pragma unroll
            for (int c = 0; c < 8; ++c) { vh[c] = hi[c]; vl[c] = lo[c]; }
            *(u16x8*)&sAh[srow][skof] = vh;
            *(u16x8*)&sAl[srow][skof] = vl;
        } else {
            *(ushort4*)&sAh[srow][skof] = make_ushort4(hi[0], hi[1], hi[2], hi[3]);
            *(ushort4*)&sAl[srow][skof] = make_ushort4(lo[0], lo[1], lo[2], lo[3]);
        }
        __syncthreads();

        // ---- B fragments from global (pre-transposed, L2-resident) ----
        s16x8 bh[4], bl[4];
        #pragma unroll
        for (int nf = 0; nf < 4; ++nf) {
            const size_t woff = (size_t)(bn + nw * 64 + nf * 16 + l15) * 256 + k0 + l4 * 8;
            bh[nf] = *(const s16x8*)(Wh + woff);
            bl[nf] = *(const s16x8*)(Wl + woff);
        }
        // ---- A fragments from LDS ----
        s16x8 ah[MF], al[MF];
        #pragma unroll
        for (int mf = 0; mf < MF; ++mf) {
            const int m = mw * WM + mf * 16 + l15;
            ah[mf] = *(const s16x8*)&sAh[m][l4 * 8];
            al[mf] = *(const s16x8*)&sAl[m][l4 * 8];
        }
        // ---- split-bf16 MFMA: Ah*Bh + Ah*Bl + Al*Bh ----
        #pragma unroll
        for (int mf = 0; mf < MF; ++mf)
            #pragma unroll
            for (int nf = 0; nf < 4; ++nf) {
                acc[mf][nf] = __builtin_amdgcn_mfma_f32_16x16x32_bf16(ah[mf], bh[nf], acc[mf][nf], 0, 0, 0);
                acc[mf][nf] = __builtin_amdgcn_mfma_f32_16x16x32_bf16(ah[mf], bl[nf], acc[mf][nf], 0, 0, 0);
                acc[mf][nf] = __builtin_amdgcn_mfma_f32_16x16x32_bf16(al[mf], bh[nf], acc[mf][nf], 0, 0, 0);
            }
    }

    // ---- epilogue ----
    #pragma unroll
    for (int mf = 0; mf < MF; ++mf) {
        const int row0 = bm + mw * WM + mf * 16 + l4 * 4;
        #pragma unroll
        for (int i = 0; i < 4; ++i) {
            const int row = row0 + i;
            if (row < M) {
                #pragma unroll
                for (int nf = 0; nf < 4; ++nf) {
                    const int col = bn + nw * 64 + nf * 16 + l15;
                    C[(size_t)row * ldc + col] = acc[mf][nf][i] + bias[col];
                }
            }
        }
    }
}

// ---------------------------------------------------------------------------
// Temporal attention: q [N,256], kv [N*T,512] (k cols 0-255, v 256-511)
// ctx may alias q (each thread reads its q element before writing ctx).
// ---------------------------------------------------------------------------
__global__ __launch_bounds__(256) void attn_t(
    const float* q, const float* kv, const int* __restrict__ tmask, float* ctx)
{
    const int n   = blockIdx.x;
    const int tid = threadIdx.x;
    const float scale = 0.1767766952966369f;  // 1/sqrt(32)

    const float qv = q[(size_t)n * 256 + tid];
    float s[TT];
    #pragma unroll
    for (int t = 0; t < TT; ++t) {
        float p = qv * kv[((size_t)n * TT + t) * 512 + tid];
        p += __shfl_xor(p, 16);
        p += __shfl_xor(p, 8);
        p += __shfl_xor(p, 4);
        p += __shfl_xor(p, 2);
        p += __shfl_xor(p, 1);
        s[t] = (tmask[n * TT + t] == 0) ? NEGV : p * scale;
    }
    float m = s[0];
    #pragma unroll
    for (int t = 1; t < TT; ++t) m = fmaxf(m, s[t]);
    float l = 0.f, p[TT];
    #pragma unroll
    for (int t = 0; t < TT; ++t) { p[t] = expf(s[t] - m); l += p[t]; }
    const float inv = 1.0f / l;
    float acc = 0.f;
    #pragma unroll
    for (int t = 0; t < TT; ++t)
        acc += p[t] * kv[((size_t)n * TT + t) * 512 + 256 + tid];
    ctx[(size_t)n * 256 + tid] = acc * inv;
}

// ---------------------------------------------------------------------------
// Spatial attention: sqkv [N,768] (sq 0-255, k 256-511, v 512-767)
// ---------------------------------------------------------------------------
__global__ __launch_bounds__(256) void attn_s(
    const float* __restrict__ sqkv, const int* __restrict__ nbrs,
    const int* __restrict__ smask, float* __restrict__ sctx)
{
    const int n   = blockIdx.x;
    const int tid = threadIdx.x;
    const float scale = 0.1767766952966369f;

    __shared__ int nb[KK];
    __shared__ int mk[KK];
    if (tid < KK) {
        nb[tid] = nbrs[n * KK + tid];
        mk[tid] = smask[n * KK + tid];
    }
    __syncthreads();

    const float qv = sqkv[(size_t)n * 768 + tid];
    float s[KK];
    #pragma unroll
    for (int j = 0; j < KK; ++j) {
        float p = qv * sqkv[(size_t)nb[j] * 768 + 256 + tid];
        p += __shfl_xor(p, 16);
        p += __shfl_xor(p, 8);
        p += __shfl_xor(p, 4);
        p += __shfl_xor(p, 2);
        p += __shfl_xor(p, 1);
        s[j] = (mk[j] == 0) ? NEGV : p * scale;
    }
    float m = s[0];
    #pragma unroll
    for (int j = 1; j < KK; ++j) m = fmaxf(m, s[j]);
    float l = 0.f;
    #pragma unroll
    for (int j = 0; j < KK; ++j) { s[j] = expf(s[j] - m); l += s[j]; }
    const float inv = 1.0f / l;
    float acc = 0.f;
    #pragma unroll
    for (int j = 0; j < KK; ++j)
        acc += s[j] * sqkv[(size_t)nb[j] * 768 + 512 + tid];
    sctx[(size_t)n * 256 + tid] = acc * inv;
}

// ---------------------------------------------------------------------------
extern "C" void kernel_launch(void* const* d_in, const int* in_sizes, int n_in,
                              void* d_out, int out_size, void* d_ws, size_t ws_size,
                              hipStream_t stream)
{
    const float* x   = (const float*)d_in[0];
    const float* tWq = (const float*)d_in[1];
    const float* tbq = (const float*)d_in[2];
    const float* tWk = (const float*)d_in[3];
    const float* tbk = (const float*)d_in[4];
    const float* tWv = (const float*)d_in[5];
    const float* tbv = (const float*)d_in[6];
    const float* tWo = (const float*)d_in[7];
    const float* tbo = (const float*)d_in[8];
    const float* sWq = (const float*)d_in[9];
    const float* sbq = (const float*)d_in[10];
    const float* sWk = (const float*)d_in[11];
    const float* sbk = (const float*)d_in[12];
    const float* sWv = (const float*)d_in[13];
    const float* sbv = (const float*)d_in[14];
    const float* sWo = (const float*)d_in[15];
    const float* sbo = (const float*)d_in[16];
    const int* nbrs  = (const int*)d_in[17];
    const int* tmask = (const int*)d_in[18];
    const int* smask = (const int*)d_in[19];
    float* out = (float*)d_out;

    const int N  = in_sizes[0] / (TT * 256);  // 10000
    const int MT = N * TT;                    // 50000

    // workspace: weights (split, transposed, concatenated) + reused f32 buffers
    unsigned short* wth = (unsigned short*)d_ws;          // [2048][256]
    unsigned short* wtl = wth + (size_t)2048 * 256;       // [2048][256]
    float* bc   = (float*)(wtl + (size_t)2048 * 256);     // [2048]
    float* big  = bc + 2048;
    float* kvbuf = big;                                   // [MT*512]
    float* sqkv  = big;                                   // [N*768]  (kv dead)
    float* htb   = big + (size_t)10'000'000;              // [N*256]  (inside dead kv)
    float* qbuf  = big + (size_t)MT * 512;                // [N*256], also ctx & sctx

    dim3 pgrid(4, 4), pblk(256);
    // weight rows: kv=[0,512) q=[512,768) ht=[768,1024) s=[1024,1792) out=[1792,2048)
    prep_w<<<pgrid, pblk, 0, stream>>>(tWk, tbk, wth + (size_t)   0 * 256, wtl + (size_t)   0 * 256, bc +    0);
    prep_w<<<pgrid, pblk, 0, stream>>>(tWv, tbv, wth + (size_t) 256 * 256, wtl + (size_t) 256 * 256, bc +  256);
    prep_w<<<pgrid, pblk, 0, stream>>>(tWq, tbq, wth + (size_t) 512 * 256, wtl + (size_t) 512 * 256, bc +  512);
    prep_w<<<pgrid, pblk, 0, stream>>>(tWo, tbo, wth + (size_t) 768 * 256, wtl + (size_t) 768 * 256, bc +  768);
    prep_w<<<pgrid, pblk, 0, stream>>>(sWq, sbq, wth + (size_t)1024 * 256, wtl + (size_t)1024 * 256, bc + 1024);
    prep_w<<<pgrid, pblk, 0, stream>>>(sWk, sbk, wth + (size_t)1280 * 256, wtl + (size_t)1280 * 256, bc + 1280);
    prep_w<<<pgrid, pblk, 0, stream>>>(sWv, sbv, wth + (size_t)1536 * 256, wtl + (size_t)1536 * 256, bc + 1536);
    prep_w<<<pgrid, pblk, 0, stream>>>(sWo, sbo, wth + (size_t)1792 * 256, wtl + (size_t)1792 * 256, bc + 1792);

    dim3 blk(512);
    // fused k+v projection: [MT x 512]
    gemm_mfma<128><<<dim3((MT + 127) / 128, 2), blk, 0, stream>>>(
        x, 256, MT, wth, wtl, bc, kvbuf, 512);
    // q projection (strided A: last timestep)
    gemm_mfma<64><<<dim3((N + 63) / 64, 1), blk, 0, stream>>>(
        x + (TT - 1) * 256, TT * 256, N, wth + (size_t)512 * 256, wtl + (size_t)512 * 256, bc + 512, qbuf, 256);
    // temporal attention (ctx in-place over qbuf)
    attn_t<<<N, dim3(256), 0, stream>>>(qbuf, kvbuf, tmask, qbuf);
    // h_t projection
    gemm_mfma<64><<<dim3((N + 63) / 64, 1), blk, 0, stream>>>(
        qbuf, 256, N, wth + (size_t)768 * 256, wtl + (size_t)768 * 256, bc + 768, htb, 256);
    // fused spatial q/k/v projection: [N x 768]
    gemm_mfma<64><<<dim3((N + 63) / 64, 3), blk, 0, stream>>>(
        htb, 256, N, wth + (size_t)1024 * 256, wtl + (size_t)1024 * 256, bc + 1024, sqkv, 768);
    // spatial attention (sctx over qbuf; qbuf dead after h_t projection)
    attn_s<<<N, dim3(256), 0, stream>>>(sqkv, nbrs, smask, qbuf);
    // output projection
    gemm_mfma<64><<<dim3((N + 63) / 64, 1), blk, 0, stream>>>(
        qbuf, 256, N, wth + (size_t)1792 * 256, wtl + (size_t)1792 * 256, bc + 1792, out, 256);
}

// Round 3
// 352.580 us; speedup vs baseline: 1.5146x; 1.2697x over previous
//
#include <hip/hip_runtime.h>

constexpr int TT = 5;     // temporal length
constexpr int KK = 25;    // spatial neighbors
#define NEGV -1e10f

typedef __attribute__((ext_vector_type(8))) short s16x8;
typedef __attribute__((ext_vector_type(4))) float f32x4;

__device__ __forceinline__ unsigned short f2bf(float f) {
    union { float f; unsigned u; } v; v.f = f;
    unsigned r = v.u + 0x7fffu + ((v.u >> 16) & 1u);
    return (unsigned short)(r >> 16);
}
__device__ __forceinline__ float bf2f(unsigned short b) {
    union { unsigned u; float f; } v; v.u = ((unsigned)b) << 16;
    return v.f;
}
// async global -> LDS direct copy, 16 B per lane (wave-uniform LDS base + lane*16)
__device__ __forceinline__ void gload16(const void* g, void* l) {
    __builtin_amdgcn_global_load_lds(
        (const __attribute__((address_space(1))) unsigned int*)g,
        (__attribute__((address_space(3))) unsigned int*)l, 16, 0, 0);
}

// ---------------------------------------------------------------------------
// Weight prep (ONE launch): W[z] [256k x 256n] f32 -> wth/wtl [z*256+n][k] bf16
// hi/lo split; biases concatenated. grid (4,4,8), block 256.
// ---------------------------------------------------------------------------
struct PrepArgs { const float* W[8]; const float* b[8]; };

__global__ __launch_bounds__(256) void prep_w8(
    PrepArgs pa, unsigned short* __restrict__ wth,
    unsigned short* __restrict__ wtl, float* __restrict__ bc)
{
    __shared__ float sT[64][65];
    const int z = blockIdx.z;
    const float* W = pa.W[z];
    unsigned short* wh = wth + (size_t)z * 256 * 256;
    unsigned short* wl = wtl + (size_t)z * 256 * 256;
    const int t  = threadIdx.x;
    const int k0 = blockIdx.x * 64, n0 = blockIdx.y * 64;
    const int kk = t >> 2;
    #pragma unroll
    for (int c = 0; c < 4; ++c) {
        const int col = (t & 3) * 16 + c * 4;
        float4 v = *(const float4*)(W + (size_t)(k0 + kk) * 256 + n0 + col);
        sT[kk][col] = v.x; sT[kk][col + 1] = v.y; sT[kk][col + 2] = v.z; sT[kk][col + 3] = v.w;
    }
    __syncthreads();
    const int n = t >> 2, ks = (t & 3) * 16;
    unsigned short* ph = wh + (size_t)(n0 + n) * 256 + k0 + ks;
    unsigned short* pl = wl + (size_t)(n0 + n) * 256 + k0 + ks;
    ushort4 vh, vl;
    #pragma unroll
    for (int j0 = 0; j0 < 16; j0 += 4) {
        #pragma unroll
        for (int j = 0; j < 4; ++j) {
            float f = sT[ks + j0 + j][n];
            unsigned short h = f2bf(f);
            unsigned short lo = f2bf(f - bf2f(h));
            ((unsigned short*)&vh)[j] = h;
            ((unsigned short*)&vl)[j] = lo;
        }
        *(ushort4*)(ph + j0) = vh;
        *(ushort4*)(pl + j0) = vl;
    }
    if (blockIdx.x == 0 && blockIdx.y == 0) bc[z * 256 + t] = pa.b[z][t];
}

// ---------------------------------------------------------------------------
// x f32 -> xh/xl bf16 (hi/lo split), vectorized float4.
// ---------------------------------------------------------------------------
__global__ __launch_bounds__(256) void split_x(
    const float* __restrict__ x, unsigned short* __restrict__ xh,
    unsigned short* __restrict__ xl, int n4)
{
    for (int i = blockIdx.x * 256 + threadIdx.x; i < n4; i += gridDim.x * 256) {
        float4 v = ((const float4*)x)[i];
        ushort4 h, lo;
        h.x = f2bf(v.x); lo.x = f2bf(v.x - bf2f(h.x));
        h.y = f2bf(v.y); lo.y = f2bf(v.y - bf2f(h.y));
        h.z = f2bf(v.z); lo.z = f2bf(v.z - bf2f(h.z));
        h.w = f2bf(v.w); lo.w = f2bf(v.w - bf2f(h.w));
        ((ushort4*)xh)[i] = h;
        ((ushort4*)xl)[i] = lo;
    }
}

// ---------------------------------------------------------------------------
// Split-bf16 MFMA GEMM, m97 structure: BM x 128 tile, BK=32, 256 thr = 4 waves
// (2x2), global_load_lds(16B) staging for A(hi,lo) and B(hi,lo), linear LDS,
// 2 barriers per k-step. A pre-split bf16 [.,256] row-major (stride lda).
// W pre-split/transposed [n][k]. OM: 0 = f32 out, 1 = bf16 out, 2 = hi/lo pair.
// ---------------------------------------------------------------------------
template<int BM, int OM>
__global__ __launch_bounds__(256) void gemm_sb(
    const unsigned short* __restrict__ Ah, const unsigned short* __restrict__ Al,
    int lda, int M,
    const unsigned short* __restrict__ Wh, const unsigned short* __restrict__ Wl,
    const float* __restrict__ bias,
    float* __restrict__ Cf, unsigned short* __restrict__ Ch,
    unsigned short* __restrict__ Cl, int ldc)
{
    constexpr int APW = BM / 64;   // A 1KB-segments per wave (128->2, 64->1)
    constexpr int MF  = BM / 32;   // M fragments per wave
    __shared__ unsigned short sAh[BM * 32], sAl[BM * 32];
    __shared__ unsigned short sBh[128 * 32], sBl[128 * 32];

    const int tid = threadIdx.x;
    const int l   = tid & 63, w = tid >> 6;
    const int l15 = l & 15, l4 = l >> 4;
    const int wm  = w >> 1, wn = w & 1;
    const int bm  = blockIdx.x * BM;
    const int bn  = blockIdx.y * 128;

    // per-lane staging source offsets (elements); row-clamp for M tail
    const int srow = l >> 2, sc = (l & 3) * 8;
    size_t aoff[APW];
    #pragma unroll
    for (int j = 0; j < APW; ++j) {
        int r = bm + (w * APW + j) * 16 + srow;
        if (r > M - 1) r = M - 1;
        aoff[j] = (size_t)r * lda + sc;
    }
    size_t boff[2];
    #pragma unroll
    for (int j = 0; j < 2; ++j)
        boff[j] = (size_t)(bn + (w * 2 + j) * 16 + srow) * 256 + sc;

    f32x4 acc[MF][4];
    #pragma unroll
    for (int i = 0; i < MF; ++i)
        #pragma unroll
        for (int j = 0; j < 4; ++j) acc[i][j] = f32x4{0.f, 0.f, 0.f, 0.f};

    for (int k0 = 0; k0 < 256; k0 += 32) {
        // async stage this k-slice (direct to LDS, no VGPR round-trip)
        #pragma unroll
        for (int j = 0; j < APW; ++j) {
            const int sg = (w * APW + j) * 512;
            gload16(Ah + aoff[j] + k0, sAh + sg);
            gload16(Al + aoff[j] + k0, sAl + sg);
        }
        #pragma unroll
        for (int j = 0; j < 2; ++j) {
            const int sg = (w * 2 + j) * 512;
            gload16(Wh + boff[j] + k0, sBh + sg);
            gload16(Wl + boff[j] + k0, sBl + sg);
        }
        __syncthreads();   // compiler drains vmcnt before barrier -> LDS valid

        s16x8 ah[MF], av[MF], bh[4], bv[4];
        #pragma unroll
        for (int mf = 0; mf < MF; ++mf) {
            const int r = wm * (BM / 2) + mf * 16 + l15;
            ah[mf] = *(const s16x8*)(sAh + r * 32 + l4 * 8);
            av[mf] = *(const s16x8*)(sAl + r * 32 + l4 * 8);
        }
        #pragma unroll
        for (int nf = 0; nf < 4; ++nf) {
            const int r = wn * 64 + nf * 16 + l15;
            bh[nf] = *(const s16x8*)(sBh + r * 32 + l4 * 8);
            bv[nf] = *(const s16x8*)(sBl + r * 32 + l4 * 8);
        }
        #pragma unroll
        for (int mf = 0; mf < MF; ++mf)
            #pragma unroll
            for (int nf = 0; nf < 4; ++nf) {
                acc[mf][nf] = __builtin_amdgcn_mfma_f32_16x16x32_bf16(ah[mf], bh[nf], acc[mf][nf], 0, 0, 0);
                acc[mf][nf] = __builtin_amdgcn_mfma_f32_16x16x32_bf16(ah[mf], bv[nf], acc[mf][nf], 0, 0, 0);
                acc[mf][nf] = __builtin_amdgcn_mfma_f32_16x16x32_bf16(av[mf], bh[nf], acc[mf][nf], 0, 0, 0);
            }
        __syncthreads();   // LDS reads done before next-iter staging
    }

    // epilogue: bias add + store (f32 / bf16 / bf16 hi+lo pair)
    #pragma unroll
    for (int mf = 0; mf < MF; ++mf) {
        const int row0 = bm + wm * (BM / 2) + mf * 16 + l4 * 4;
        #pragma unroll
        for (int nf = 0; nf < 4; ++nf) {
            const int col = bn + wn * 64 + nf * 16 + l15;
            const float bs = bias[col];
            #pragma unroll
            for (int i = 0; i < 4; ++i) {
                const int row = row0 + i;
                if (row < M) {
                    const float v = acc[mf][nf][i] + bs;
                    const size_t o = (size_t)row * ldc + col;
                    if (OM == 0) {
                        Cf[o] = v;
                    } else if (OM == 1) {
                        Ch[o] = f2bf(v);
                    } else {
                        unsigned short h = f2bf(v);
                        Ch[o] = h;
                        Cl[o] = f2bf(v - bf2f(h));
                    }
                }
            }
        }
    }
}

// ---------------------------------------------------------------------------
// Temporal attention: q f32 [N,256], kv bf16 [N*T,512] -> ctx hi/lo bf16.
// ---------------------------------------------------------------------------
__global__ __launch_bounds__(256) void attn_t(
    const float* __restrict__ q, const unsigned short* __restrict__ kv,
    const int* __restrict__ tmask,
    unsigned short* __restrict__ ch, unsigned short* __restrict__ cl)
{
    const int n   = blockIdx.x;
    const int tid = threadIdx.x;
    const float scale = 0.1767766952966369f;  // 1/sqrt(32)

    const float qv = q[(size_t)n * 256 + tid];
    float s[TT];
    #pragma unroll
    for (int t = 0; t < TT; ++t) {
        float p = qv * bf2f(kv[((size_t)n * TT + t) * 512 + tid]);
        p += __shfl_xor(p, 16);
        p += __shfl_xor(p, 8);
        p += __shfl_xor(p, 4);
        p += __shfl_xor(p, 2);
        p += __shfl_xor(p, 1);
        s[t] = (tmask[n * TT + t] == 0) ? NEGV : p * scale;
    }
    float m = s[0];
    #pragma unroll
    for (int t = 1; t < TT; ++t) m = fmaxf(m, s[t]);
    float lsum = 0.f, p[TT];
    #pragma unroll
    for (int t = 0; t < TT; ++t) { p[t] = expf(s[t] - m); lsum += p[t]; }
    const float inv = 1.0f / lsum;
    float acc = 0.f;
    #pragma unroll
    for (int t = 0; t < TT; ++t)
        acc += p[t] * bf2f(kv[((size_t)n * TT + t) * 512 + 256 + tid]);
    const float r = acc * inv;
    const unsigned short h = f2bf(r);
    ch[(size_t)n * 256 + tid] = h;
    cl[(size_t)n * 256 + tid] = f2bf(r - bf2f(h));
}

// ---------------------------------------------------------------------------
// Spatial attention: sqkv f32 [N,768] (q|k|v) -> sctx hi/lo bf16.
// ---------------------------------------------------------------------------
__global__ __launch_bounds__(256) void attn_s(
    const float* __restrict__ sqkv, const int* __restrict__ nbrs,
    const int* __restrict__ smask,
    unsigned short* __restrict__ ch, unsigned short* __restrict__ cl)
{
    const int n   = blockIdx.x;
    const int tid = threadIdx.x;
    const float scale = 0.1767766952966369f;

    __shared__ int nb[KK];
    __shared__ int mk[KK];
    if (tid < KK) {
        nb[tid] = nbrs[n * KK + tid];
        mk[tid] = smask[n * KK + tid];
    }
    __syncthreads();

    const float qv = sqkv[(size_t)n * 768 + tid];
    float s[KK];
    #pragma unroll
    for (int j = 0; j < KK; ++j) {
        float p = qv * sqkv[(size_t)nb[j] * 768 + 256 + tid];
        p += __shfl_xor(p, 16);
        p += __shfl_xor(p, 8);
        p += __shfl_xor(p, 4);
        p += __shfl_xor(p, 2);
        p += __shfl_xor(p, 1);
        s[j] = (mk[j] == 0) ? NEGV : p * scale;
    }
    float m = s[0];
    #pragma unroll
    for (int j = 1; j < KK; ++j) m = fmaxf(m, s[j]);
    float lsum = 0.f;
    #pragma unroll
    for (int j = 0; j < KK; ++j) { s[j] = expf(s[j] - m); lsum += s[j]; }
    const float inv = 1.0f / lsum;
    float acc = 0.f;
    #pragma unroll
    for (int j = 0; j < KK; ++j)
        acc += s[j] * sqkv[(size_t)nb[j] * 768 + 512 + tid];
    const float r = acc * inv;
    const unsigned short h = f2bf(r);
    ch[(size_t)n * 256 + tid] = h;
    cl[(size_t)n * 256 + tid] = f2bf(r - bf2f(h));
}

// ---------------------------------------------------------------------------
extern "C" void kernel_launch(void* const* d_in, const int* in_sizes, int n_in,
                              void* d_out, int out_size, void* d_ws, size_t ws_size,
                              hipStream_t stream)
{
    const float* x = (const float*)d_in[0];
    const int* nbrs  = (const int*)d_in[17];
    const int* tmask = (const int*)d_in[18];
    const int* smask = (const int*)d_in[19];
    float* out = (float*)d_out;

    const int N  = in_sizes[0] / (TT * 256);  // 10000
    const int MT = N * TT;                    // 50000

    // ---- workspace layout (bytes), aggressive aliasing; peak ~115 MB ----
    unsigned short* wth = (unsigned short*)d_ws;            // [2048][256] bf16
    unsigned short* wtl = wth + (size_t)2048 * 256;
    float* bc = (float*)(wtl + (size_t)2048 * 256);         // [2048] f32
    unsigned short* xh = (unsigned short*)(bc + 2048);      // [MT*256]
    unsigned short* xl = xh + (size_t)MT * 256;             // [MT*256]
    unsigned short* kvbuf = xl + (size_t)MT * 256;          // [MT*512] bf16
    float* qbuf = (float*)(kvbuf + (size_t)MT * 512);       // [N*256] f32
    // aliases (lifetimes verified):
    unsigned short* ctxh = xh;                  // after q GEMM, xh dead
    unsigned short* ctxl = ctxh + (size_t)N * 256;
    unsigned short* hth  = xl;                  // after q GEMM, xl dead
    unsigned short* htl  = hth + (size_t)N * 256;
    float* sqkvf = (float*)kvbuf;               // after attn_t, kv dead (30.7MB < 51.2MB)
    unsigned short* sctxh = (unsigned short*)qbuf;  // after attn_t, q dead
    unsigned short* sctxl = sctxh + (size_t)N * 256;

    // ---- weight prep: rows kv=[0,512) q=[512,768) ht=[768,1024)
    //                   s(q,k,v)=[1024,1792) out=[1792,2048) ----
    PrepArgs pa;
    pa.W[0] = (const float*)d_in[3];  pa.b[0] = (const float*)d_in[4];   // tWk
    pa.W[1] = (const float*)d_in[5];  pa.b[1] = (const float*)d_in[6];   // tWv
    pa.W[2] = (const float*)d_in[1];  pa.b[2] = (const float*)d_in[2];   // tWq
    pa.W[3] = (const float*)d_in[7];  pa.b[3] = (const float*)d_in[8];   // tWo
    pa.W[4] = (const float*)d_in[9];  pa.b[4] = (const float*)d_in[10];  // sWq
    pa.W[5] = (const float*)d_in[11]; pa.b[5] = (const float*)d_in[12];  // sWk
    pa.W[6] = (const float*)d_in[13]; pa.b[6] = (const float*)d_in[14];  // sWv
    pa.W[7] = (const float*)d_in[15]; pa.b[7] = (const float*)d_in[16];  // sWo
    prep_w8<<<dim3(4, 4, 8), 256, 0, stream>>>(pa, wth, wtl, bc);

    // ---- split x into hi/lo bf16 ----
    split_x<<<2048, 256, 0, stream>>>(x, xh, xl, MT * 256 / 4);

    dim3 blk(256);
    // kv projection: [MT x 512] -> bf16
    gemm_sb<128, 1><<<dim3((MT + 127) / 128, 4), blk, 0, stream>>>(
        xh, xl, 256, MT, wth, wtl, bc, nullptr, kvbuf, nullptr, 512);
    // q projection (last timestep rows, lda = T*256) -> f32
    gemm_sb<64, 0><<<dim3((N + 63) / 64, 2), blk, 0, stream>>>(
        xh + (TT - 1) * 256, xl + (TT - 1) * 256, TT * 256, N,
        wth + (size_t)512 * 256, wtl + (size_t)512 * 256, bc + 512,
        qbuf, nullptr, nullptr, 256);
    // temporal attention -> ctx hi/lo
    attn_t<<<N, blk, 0, stream>>>(qbuf, kvbuf, tmask, ctxh, ctxl);
    // h_t projection -> hi/lo
    gemm_sb<64, 2><<<dim3((N + 63) / 64, 2), blk, 0, stream>>>(
        ctxh, ctxl, 256, N,
        wth + (size_t)768 * 256, wtl + (size_t)768 * 256, bc + 768,
        nullptr, hth, htl, 256);
    // fused spatial q/k/v projection: [N x 768] -> f32
    gemm_sb<64, 0><<<dim3((N + 63) / 64, 6), blk, 0, stream>>>(
        hth, htl, 256, N,
        wth + (size_t)1024 * 256, wtl + (size_t)1024 * 256, bc + 1024,
        sqkvf, nullptr, nullptr, 768);
    // spatial attention -> sctx hi/lo
    attn_s<<<N, blk, 0, stream>>>(sqkvf, nbrs, smask, sctxh, sctxl);
    // output projection -> f32 out
    gemm_sb<64, 0><<<dim3((N + 63) / 64, 2), blk, 0, stream>>>(
        sctxh, sctxl, 256, N,
        wth + (size_t)1792 * 256, wtl + (size_t)1792 * 256, bc + 1792,
        out, nullptr, nullptr, 256);
}

// Round 4
// 294.356 us; speedup vs baseline: 1.8142x; 1.1978x over previous
//
#include <hip/hip_runtime.h>

constexpr int TT = 5;     // temporal length
constexpr int KK = 25;    // spatial neighbors
#define NEGV -1e10f

typedef _Float16 f16;
typedef __attribute__((ext_vector_type(8))) _Float16 f16x8;
typedef __attribute__((ext_vector_type(4))) float f32x4;

// async global -> LDS direct copy, 16 B/lane (wave-uniform LDS base + lane*16)
__device__ __forceinline__ void gload16(const void* g, void* l) {
    __builtin_amdgcn_global_load_lds(
        (const __attribute__((address_space(1))) unsigned int*)g,
        (__attribute__((address_space(3))) unsigned int*)l, 16, 0, 0);
}

// bijective XCD-chunk remap (m204): blocks on one XCD get a contiguous chunk
// of the (bm-major) tile space -> A-panel reuse hits that XCD's L2.
__device__ __forceinline__ int xcd_remap(int id, int G) {
    const int c = id & 7, j = id >> 3;
    const int q = G >> 3, r = G & 7;
    const int base = (c < r) ? c * (q + 1) : r * (q + 1) + (c - r) * q;
    return base + j;
}

// ---------------------------------------------------------------------------
// Weight prep (ONE launch): W[z] [256k x 256n] f32 -> wth/wtl [z*256+n][k]
// fp16 hi/lo split; biases concatenated f32. grid (4,4,8), block 256.
// ---------------------------------------------------------------------------
struct PrepArgs { const float* W[8]; const float* b[8]; };

__global__ __launch_bounds__(256) void prep_w8(
    PrepArgs pa, f16* __restrict__ wth, f16* __restrict__ wtl,
    float* __restrict__ bc)
{
    __shared__ float sT[64][65];
    const int z = blockIdx.z;
    const float* W = pa.W[z];
    f16* wh = wth + (size_t)z * 65536;
    f16* wl = wtl + (size_t)z * 65536;
    const int t  = threadIdx.x;
    const int k0 = blockIdx.x * 64, n0 = blockIdx.y * 64;
    const int kk = t >> 2;
    #pragma unroll
    for (int c = 0; c < 4; ++c) {
        const int col = (t & 3) * 16 + c * 4;
        float4 v = *(const float4*)(W + (size_t)(k0 + kk) * 256 + n0 + col);
        sT[kk][col] = v.x; sT[kk][col + 1] = v.y; sT[kk][col + 2] = v.z; sT[kk][col + 3] = v.w;
    }
    __syncthreads();
    const int n = t >> 2, ks = (t & 3) * 16;
    f16* ph = wh + (size_t)(n0 + n) * 256 + k0 + ks;
    f16* pl = wl + (size_t)(n0 + n) * 256 + k0 + ks;
    f16x8 vh, vl;
    #pragma unroll
    for (int j0 = 0; j0 < 16; j0 += 8) {
        #pragma unroll
        for (int j = 0; j < 8; ++j) {
            const float f = sT[ks + j0 + j][n];
            const f16 h = (f16)f;
            vh[j] = h;
            vl[j] = (f16)(f - (float)h);
        }
        *(f16x8*)(ph + j0) = vh;
        *(f16x8*)(pl + j0) = vl;
    }
    if (blockIdx.x == 0 && blockIdx.y == 0) bc[z * 256 + t] = pa.b[z][t];
}

// ---------------------------------------------------------------------------
// x f32 -> fp16, 8 elems/thread (16B stores).
// ---------------------------------------------------------------------------
__global__ __launch_bounds__(256) void cvt_x(
    const float* __restrict__ x, f16* __restrict__ xh, int n8)
{
    for (int i = blockIdx.x * 256 + threadIdx.x; i < n8; i += gridDim.x * 256) {
        const float4 a = ((const float4*)x)[2 * i];
        const float4 b = ((const float4*)x)[2 * i + 1];
        f16x8 o;
        o[0] = (f16)a.x; o[1] = (f16)a.y; o[2] = (f16)a.z; o[3] = (f16)a.w;
        o[4] = (f16)b.x; o[5] = (f16)b.y; o[6] = (f16)b.z; o[7] = (f16)b.w;
        *(f16x8*)(xh + (size_t)i * 8) = o;
    }
}

// ---------------------------------------------------------------------------
// Split-W fp16 MFMA GEMM: C[M x Ntot] = A_f16 @ (Wh+Wl)^T + bias.
// Tile 128x128, BK=32, 512 thr = 8 waves (2 wm x 4 wn), per-wave 64x32 out
// (acc = 32 VGPR). global_load_lds(16B) staging, linear LDS, 2 barriers/k-step.
// 1-D grid with bijective XCD-chunk remap; GY = tiles along N.
// OM: 0 = f32 out, 1 = fp16 out.
// ---------------------------------------------------------------------------
template<int OM>
__global__ __launch_bounds__(512, 4) void gemm_f16(
    const f16* __restrict__ A, int lda, int M,
    const f16* __restrict__ Wh, const f16* __restrict__ Wl,
    const float* __restrict__ bias,
    float* __restrict__ Cf, f16* __restrict__ Ch, int ldc,
    int GY, int G)
{
    __shared__ f16 sA[128 * 32], sBh[128 * 32], sBl[128 * 32];

    const int tid = threadIdx.x;
    const int l   = tid & 63, w = tid >> 6;
    const int l15 = l & 15, l4 = l >> 4;
    const int wm  = w >> 2, wn = w & 3;

    const int p  = xcd_remap(blockIdx.x, G);
    const int bm = (p / GY) * 128;
    const int bn = (p % GY) * 128;

    // staging: wave w covers rows [w*16, w*16+16) of each 128x32 tile
    const int srow = l >> 2, sc = (l & 3) * 8;
    int ar = bm + w * 16 + srow;
    if (ar > M - 1) ar = M - 1;          // clamp reads; stores guarded
    const size_t aoff = (size_t)ar * lda + sc;
    const size_t boff = (size_t)(bn + w * 16 + srow) * 256 + sc;
    const int sbase = w * 512;           // elems (1KB per wave-segment)

    f32x4 acc[4][2];
    #pragma unroll
    for (int i = 0; i < 4; ++i)
        #pragma unroll
        for (int j = 0; j < 2; ++j) acc[i][j] = f32x4{0.f, 0.f, 0.f, 0.f};

    for (int k0 = 0; k0 < 256; k0 += 32) {
        gload16(A + aoff + k0, sA + sbase);
        gload16(Wh + boff + k0, sBh + sbase);
        gload16(Wl + boff + k0, sBl + sbase);
        __syncthreads();   // vmcnt drained by compiler before barrier

        f16x8 a[4], bh[2], bl[2];
        #pragma unroll
        for (int mf = 0; mf < 4; ++mf)
            a[mf] = *(const f16x8*)(sA + (wm * 64 + mf * 16 + l15) * 32 + l4 * 8);
        #pragma unroll
        for (int nf = 0; nf < 2; ++nf) {
            const int r = wn * 32 + nf * 16 + l15;
            bh[nf] = *(const f16x8*)(sBh + r * 32 + l4 * 8);
            bl[nf] = *(const f16x8*)(sBl + r * 32 + l4 * 8);
        }
        #pragma unroll
        for (int mf = 0; mf < 4; ++mf)
            #pragma unroll
            for (int nf = 0; nf < 2; ++nf) {
                acc[mf][nf] = __builtin_amdgcn_mfma_f32_16x16x32_f16(a[mf], bh[nf], acc[mf][nf], 0, 0, 0);
                acc[mf][nf] = __builtin_amdgcn_mfma_f32_16x16x32_f16(a[mf], bl[nf], acc[mf][nf], 0, 0, 0);
            }
        __syncthreads();   // LDS reads done before next-iter staging
    }

    // epilogue: bias + store
    #pragma unroll
    for (int mf = 0; mf < 4; ++mf) {
        const int row0 = bm + wm * 64 + mf * 16 + l4 * 4;
        #pragma unroll
        for (int nf = 0; nf < 2; ++nf) {
            const int col = bn + wn * 32 + nf * 16 + l15;
            const float bs = bias[col];
            #pragma unroll
            for (int i = 0; i < 4; ++i) {
                const int row = row0 + i;
                if (row < M) {
                    const float v = acc[mf][nf][i] + bs;
                    const size_t o = (size_t)row * ldc + col;
                    if (OM == 0) Cf[o] = v;
                    else         Ch[o] = (f16)v;
                }
            }
        }
    }
}

// ---------------------------------------------------------------------------
// Temporal attention: q f32 [N,256], kv fp16 [N*T,512] -> ctx fp16 [N,256].
// ---------------------------------------------------------------------------
__global__ __launch_bounds__(256) void attn_t(
    const float* __restrict__ q, const f16* __restrict__ kv,
    const int* __restrict__ tmask, f16* __restrict__ ctx)
{
    const int n   = blockIdx.x;
    const int tid = threadIdx.x;
    const float scale = 0.1767766952966369f;  // 1/sqrt(32)

    const float qv = q[(size_t)n * 256 + tid];
    float s[TT];
    #pragma unroll
    for (int t = 0; t < TT; ++t) {
        float p = qv * (float)kv[((size_t)n * TT + t) * 512 + tid];
        p += __shfl_xor(p, 16);
        p += __shfl_xor(p, 8);
        p += __shfl_xor(p, 4);
        p += __shfl_xor(p, 2);
        p += __shfl_xor(p, 1);
        s[t] = (tmask[n * TT + t] == 0) ? NEGV : p * scale;
    }
    float m = s[0];
    #pragma unroll
    for (int t = 1; t < TT; ++t) m = fmaxf(m, s[t]);
    float lsum = 0.f, p[TT];
    #pragma unroll
    for (int t = 0; t < TT; ++t) { p[t] = expf(s[t] - m); lsum += p[t]; }
    const float inv = 1.0f / lsum;
    float acc = 0.f;
    #pragma unroll
    for (int t = 0; t < TT; ++t)
        acc += p[t] * (float)kv[((size_t)n * TT + t) * 512 + 256 + tid];
    ctx[(size_t)n * 256 + tid] = (f16)(acc * inv);
}

// ---------------------------------------------------------------------------
// Spatial attention: sqkv f32 [N,768] (q|k|v) -> sctx fp16 [N,256].
// ---------------------------------------------------------------------------
__global__ __launch_bounds__(256) void attn_s(
    const float* __restrict__ sqkv, const int* __restrict__ nbrs,
    const int* __restrict__ smask, f16* __restrict__ sctx)
{
    const int n   = blockIdx.x;
    const int tid = threadIdx.x;
    const float scale = 0.1767766952966369f;

    __shared__ int nb[KK];
    __shared__ int mk[KK];
    if (tid < KK) {
        nb[tid] = nbrs[n * KK + tid];
        mk[tid] = smask[n * KK + tid];
    }
    __syncthreads();

    const float qv = sqkv[(size_t)n * 768 + tid];
    float s[KK];
    #pragma unroll
    for (int j = 0; j < KK; ++j) {
        float p = qv * sqkv[(size_t)nb[j] * 768 + 256 + tid];
        p += __shfl_xor(p, 16);
        p += __shfl_xor(p, 8);
        p += __shfl_xor(p, 4);
        p += __shfl_xor(p, 2);
        p += __shfl_xor(p, 1);
        s[j] = (mk[j] == 0) ? NEGV : p * scale;
    }
    float m = s[0];
    #pragma unroll
    for (int j = 1; j < KK; ++j) m = fmaxf(m, s[j]);
    float lsum = 0.f;
    #pragma unroll
    for (int j = 0; j < KK; ++j) { s[j] = expf(s[j] - m); lsum += s[j]; }
    const float inv = 1.0f / lsum;
    float acc = 0.f;
    #pragma unroll
    for (int j = 0; j < KK; ++j)
        acc += s[j] * sqkv[(size_t)nb[j] * 768 + 512 + tid];
    sctx[(size_t)n * 256 + tid] = (f16)(acc * inv);
}

// ---------------------------------------------------------------------------
extern "C" void kernel_launch(void* const* d_in, const int* in_sizes, int n_in,
                              void* d_out, int out_size, void* d_ws, size_t ws_size,
                              hipStream_t stream)
{
    const float* x = (const float*)d_in[0];
    const int* nbrs  = (const int*)d_in[17];
    const int* tmask = (const int*)d_in[18];
    const int* smask = (const int*)d_in[19];
    float* out = (float*)d_out;

    const int N  = in_sizes[0] / (TT * 256);  // 10000
    const int MT = N * TT;                    // 50000

    // ---- workspace layout (~105 MB peak) ----
    f16* wth = (f16*)d_ws;                          // [2048][256]
    f16* wtl = wth + (size_t)2048 * 256;
    float* bc = (float*)(wtl + (size_t)2048 * 256); // [2048]
    f16* xh = (f16*)(bc + 2048);                    // [MT*256]
    f16* kvbuf = xh + (size_t)MT * 256;             // [MT*512]
    float* qbuf = (float*)(kvbuf + (size_t)MT * 512);  // [N*256] f32
    f16* ctx  = (f16*)(qbuf + (size_t)N * 256);     // [N*256]
    f16* ht   = ctx + (size_t)N * 256;              // [N*256]
    f16* sctx = ht + (size_t)N * 256;               // [N*256]
    float* sqkvf = (float*)kvbuf;                   // [N*768] alias (kv dead after attn_t)

    // ---- weight prep: rows kv=[0,512) q=[512,768) ht=[768,1024)
    //      s(q,k,v)=[1024,1792) out=[1792,2048) ----
    PrepArgs pa;
    pa.W[0] = (const float*)d_in[3];  pa.b[0] = (const float*)d_in[4];   // tWk
    pa.W[1] = (const float*)d_in[5];  pa.b[1] = (const float*)d_in[6];   // tWv
    pa.W[2] = (const float*)d_in[1];  pa.b[2] = (const float*)d_in[2];   // tWq
    pa.W[3] = (const float*)d_in[7];  pa.b[3] = (const float*)d_in[8];   // tWo
    pa.W[4] = (const float*)d_in[9];  pa.b[4] = (const float*)d_in[10];  // sWq
    pa.W[5] = (const float*)d_in[11]; pa.b[5] = (const float*)d_in[12];  // sWk
    pa.W[6] = (const float*)d_in[13]; pa.b[6] = (const float*)d_in[14];  // sWv
    pa.W[7] = (const float*)d_in[15]; pa.b[7] = (const float*)d_in[16];  // sWo
    prep_w8<<<dim3(4, 4, 8), 256, 0, stream>>>(pa, wth, wtl, bc);

    // ---- x -> fp16 ----
    cvt_x<<<2048, 256, 0, stream>>>(x, xh, MT * 256 / 8);

    dim3 blk(512);
    const int GBM_T = (MT + 127) / 128;   // 391
    const int GBM_N = (N + 127) / 128;    // 79

    // kv projection: [MT x 512] -> fp16
    gemm_f16<1><<<GBM_T * 4, blk, 0, stream>>>(
        xh, 256, MT, wth, wtl, bc, nullptr, kvbuf, 512, 4, GBM_T * 4);
    // q projection (last timestep rows) -> f32
    gemm_f16<0><<<GBM_N * 2, blk, 0, stream>>>(
        xh + (TT - 1) * 256, TT * 256, N,
        wth + (size_t)512 * 256, wtl + (size_t)512 * 256, bc + 512,
        qbuf, nullptr, 256, 2, GBM_N * 2);
    // temporal attention -> ctx fp16
    attn_t<<<N, dim3(256), 0, stream>>>(qbuf, kvbuf, tmask, ctx);
    // h_t projection -> fp16
    gemm_f16<1><<<GBM_N * 2, blk, 0, stream>>>(
        ctx, 256, N,
        wth + (size_t)768 * 256, wtl + (size_t)768 * 256, bc + 768,
        nullptr, ht, 256, 2, GBM_N * 2);
    // fused spatial q/k/v projection: [N x 768] -> f32 (aliases dead kv)
    gemm_f16<0><<<GBM_N * 6, blk, 0, stream>>>(
        ht, 256, N,
        wth + (size_t)1024 * 256, wtl + (size_t)1024 * 256, bc + 1024,
        sqkvf, nullptr, 768, 6, GBM_N * 6);
    // spatial attention -> sctx fp16
    attn_s<<<N, dim3(256), 0, stream>>>(sqkvf, nbrs, smask, sctx);
    // output projection -> f32 out
    gemm_f16<0><<<GBM_N * 2, blk, 0, stream>>>(
        sctx, 256, N,
        wth + (size_t)1792 * 256, wtl + (size_t)1792 * 256, bc + 1792,
        out, nullptr, 256, 2, GBM_N * 2);
}

// Round 5
// 250.955 us; speedup vs baseline: 2.1280x; 1.1729x over previous
//
#include <hip/hip_runtime.h>

constexpr int TT = 5;     // temporal length
constexpr int KK = 25;    // spatial neighbors
#define NEGV -1e10f

typedef _Float16 f16;
typedef __attribute__((ext_vector_type(8))) _Float16 f16x8;
typedef __attribute__((ext_vector_type(4))) _Float16 f16x4;
typedef __attribute__((ext_vector_type(4))) float f32x4;

// async global -> LDS direct copy, 16 B/lane (wave-uniform LDS base + lane*16)
__device__ __forceinline__ void gload16(const void* g, void* l) {
    __builtin_amdgcn_global_load_lds(
        (const __attribute__((address_space(1))) unsigned int*)g,
        (__attribute__((address_space(3))) unsigned int*)l, 16, 0, 0);
}

// bijective XCD-chunk remap (m204): blocks on one XCD get a contiguous chunk
// of the tile space -> panel/neighbor reuse hits that XCD's L2.
__device__ __forceinline__ int xcd_remap(int id, int G) {
    const int c = id & 7, j = id >> 3;
    const int q = G >> 3, r = G & 7;
    const int base = (c < r) ? c * (q + 1) : r * (q + 1) + (c - r) * q;
    return base + j;
}

// ---------------------------------------------------------------------------
// Weight prep (ONE launch): W[z] [256k x 256n] f32 -> wth/wtl [z*256+n][k]
// fp16 hi/lo split; biases concatenated f32. grid (4,4,8), block 256.
// ---------------------------------------------------------------------------
struct PrepArgs { const float* W[8]; const float* b[8]; };

__global__ __launch_bounds__(256) void prep_w8(
    PrepArgs pa, f16* __restrict__ wth, f16* __restrict__ wtl,
    float* __restrict__ bc)
{
    __shared__ float sT[64][65];
    const int z = blockIdx.z;
    const float* W = pa.W[z];
    f16* wh = wth + (size_t)z * 65536;
    f16* wl = wtl + (size_t)z * 65536;
    const int t  = threadIdx.x;
    const int k0 = blockIdx.x * 64, n0 = blockIdx.y * 64;
    const int kk = t >> 2;
    #pragma unroll
    for (int c = 0; c < 4; ++c) {
        const int col = (t & 3) * 16 + c * 4;
        float4 v = *(const float4*)(W + (size_t)(k0 + kk) * 256 + n0 + col);
        sT[kk][col] = v.x; sT[kk][col + 1] = v.y; sT[kk][col + 2] = v.z; sT[kk][col + 3] = v.w;
    }
    __syncthreads();
    const int n = t >> 2, ks = (t & 3) * 16;
    f16* ph = wh + (size_t)(n0 + n) * 256 + k0 + ks;
    f16* pl = wl + (size_t)(n0 + n) * 256 + k0 + ks;
    f16x8 vh, vl;
    #pragma unroll
    for (int j0 = 0; j0 < 16; j0 += 8) {
        #pragma unroll
        for (int j = 0; j < 8; ++j) {
            const float f = sT[ks + j0 + j][n];
            const f16 h = (f16)f;
            vh[j] = h;
            vl[j] = (f16)(f - (float)h);
        }
        *(f16x8*)(ph + j0) = vh;
        *(f16x8*)(pl + j0) = vl;
    }
    if (blockIdx.x == 0 && blockIdx.y == 0) bc[z * 256 + t] = pa.b[z][t];
}

// ---------------------------------------------------------------------------
// x f32 -> fp16, 8 elems/thread (16B stores).
// ---------------------------------------------------------------------------
__global__ __launch_bounds__(256) void cvt_x(
    const float* __restrict__ x, f16* __restrict__ xh, int n8)
{
    for (int i = blockIdx.x * 256 + threadIdx.x; i < n8; i += gridDim.x * 256) {
        const float4 a = ((const float4*)x)[2 * i];
        const float4 b = ((const float4*)x)[2 * i + 1];
        f16x8 o;
        o[0] = (f16)a.x; o[1] = (f16)a.y; o[2] = (f16)a.z; o[3] = (f16)a.w;
        o[4] = (f16)b.x; o[5] = (f16)b.y; o[6] = (f16)b.z; o[7] = (f16)b.w;
        *(f16x8*)(xh + (size_t)i * 8) = o;
    }
}

// ---------------------------------------------------------------------------
// Split-W fp16 MFMA GEMM: C[M x Ntot] = A_f16 @ (Wh+Wl)^T + bias.
// Tile 128x128, BK=32, 512 thr = 8 waves (2 wm x 4 wn), per-wave 64x32 out.
// global_load_lds(16B) staging, linear LDS, 2 barriers/k-step, XCD remap.
// OM: 0 = f32 out, 1 = fp16 out.
// ---------------------------------------------------------------------------
template<int OM>
__global__ __launch_bounds__(512, 4) void gemm_f16(
    const f16* __restrict__ A, int lda, int M,
    const f16* __restrict__ Wh, const f16* __restrict__ Wl,
    const float* __restrict__ bias,
    float* __restrict__ Cf, f16* __restrict__ Ch, int ldc,
    int GY, int G)
{
    __shared__ f16 sA[128 * 32], sBh[128 * 32], sBl[128 * 32];

    const int tid = threadIdx.x;
    const int l   = tid & 63, w = tid >> 6;
    const int l15 = l & 15, l4 = l >> 4;
    const int wm  = w >> 2, wn = w & 3;

    const int p  = xcd_remap(blockIdx.x, G);
    const int bm = (p / GY) * 128;
    const int bn = (p % GY) * 128;

    const int srow = l >> 2, sc = (l & 3) * 8;
    int ar = bm + w * 16 + srow;
    if (ar > M - 1) ar = M - 1;          // clamp reads; stores guarded
    const size_t aoff = (size_t)ar * lda + sc;
    const size_t boff = (size_t)(bn + w * 16 + srow) * 256 + sc;
    const int sbase = w * 512;

    f32x4 acc[4][2];
    #pragma unroll
    for (int i = 0; i < 4; ++i)
        #pragma unroll
        for (int j = 0; j < 2; ++j) acc[i][j] = f32x4{0.f, 0.f, 0.f, 0.f};

    for (int k0 = 0; k0 < 256; k0 += 32) {
        gload16(A + aoff + k0, sA + sbase);
        gload16(Wh + boff + k0, sBh + sbase);
        gload16(Wl + boff + k0, sBl + sbase);
        __syncthreads();

        f16x8 a[4], bh[2], bl[2];
        #pragma unroll
        for (int mf = 0; mf < 4; ++mf)
            a[mf] = *(const f16x8*)(sA + (wm * 64 + mf * 16 + l15) * 32 + l4 * 8);
        #pragma unroll
        for (int nf = 0; nf < 2; ++nf) {
            const int r = wn * 32 + nf * 16 + l15;
            bh[nf] = *(const f16x8*)(sBh + r * 32 + l4 * 8);
            bl[nf] = *(const f16x8*)(sBl + r * 32 + l4 * 8);
        }
        #pragma unroll
        for (int mf = 0; mf < 4; ++mf)
            #pragma unroll
            for (int nf = 0; nf < 2; ++nf) {
                acc[mf][nf] = __builtin_amdgcn_mfma_f32_16x16x32_f16(a[mf], bh[nf], acc[mf][nf], 0, 0, 0);
                acc[mf][nf] = __builtin_amdgcn_mfma_f32_16x16x32_f16(a[mf], bl[nf], acc[mf][nf], 0, 0, 0);
            }
        __syncthreads();
    }

    #pragma unroll
    for (int mf = 0; mf < 4; ++mf) {
        const int row0 = bm + wm * 64 + mf * 16 + l4 * 4;
        #pragma unroll
        for (int nf = 0; nf < 2; ++nf) {
            const int col = bn + wn * 32 + nf * 16 + l15;
            const float bs = bias[col];
            #pragma unroll
            for (int i = 0; i < 4; ++i) {
                const int row = row0 + i;
                if (row < M) {
                    const float v = acc[mf][nf][i] + bs;
                    const size_t o = (size_t)row * ldc + col;
                    if (OM == 0) Cf[o] = v;
                    else         Ch[o] = (f16)v;
                }
            }
        }
    }
}

// ---------------------------------------------------------------------------
// Temporal attention, wave-per-node: lane = (h, dq), 4 d-elems per lane.
// q fp16 [N,256], kv fp16 [N*T,512] -> ctx fp16 [N,256]. Block = 4 nodes.
// Dot partial in-register (8 ops), reduce over 8 lanes (3 shfls), online SM.
// ---------------------------------------------------------------------------
__global__ __launch_bounds__(256) void attn_t(
    const f16* __restrict__ q, const f16* __restrict__ kv,
    const int* __restrict__ tmask, f16* __restrict__ ctx)
{
    const int tid = threadIdx.x;
    const int wv = tid >> 6, l = tid & 63;
    const int n = blockIdx.x * 4 + wv;
    const int col = ((l >> 3) * 32) + (l & 7) * 4;   // h*32 + dq*4
    const float scale = 0.1767766952966369f;          // 1/sqrt(32)

    const f16x4 qv = *(const f16x4*)(q + (size_t)n * 256 + col);
    const float q0 = (float)qv[0], q1 = (float)qv[1], q2 = (float)qv[2], q3 = (float)qv[3];

    float m = -3.0e38f, lsum = 0.f;
    float a0 = 0.f, a1 = 0.f, a2 = 0.f, a3 = 0.f;
    #pragma unroll
    for (int t = 0; t < TT; ++t) {
        const size_t row = ((size_t)n * TT + t) * 512;
        const f16x4 kk = *(const f16x4*)(kv + row + col);
        const f16x4 vv = *(const f16x4*)(kv + row + 256 + col);
        float p = q0 * (float)kk[0] + q1 * (float)kk[1]
                + q2 * (float)kk[2] + q3 * (float)kk[3];
        p += __shfl_xor(p, 1);
        p += __shfl_xor(p, 2);
        p += __shfl_xor(p, 4);
        const float s  = (tmask[n * TT + t] == 0) ? NEGV : p * scale;
        const float mn = fmaxf(m, s);
        const float sc = exp2f((m - mn) * 1.44269504f);
        const float pe = exp2f((s - mn) * 1.44269504f);
        lsum = lsum * sc + pe;
        a0 = a0 * sc + pe * (float)vv[0];
        a1 = a1 * sc + pe * (float)vv[1];
        a2 = a2 * sc + pe * (float)vv[2];
        a3 = a3 * sc + pe * (float)vv[3];
        m = mn;
    }
    const float inv = 1.0f / lsum;
    f16x4 o;
    o[0] = (f16)(a0 * inv); o[1] = (f16)(a1 * inv);
    o[2] = (f16)(a2 * inv); o[3] = (f16)(a3 * inv);
    *(f16x4*)(ctx + (size_t)n * 256 + col) = o;
}

// ---------------------------------------------------------------------------
// Spatial attention, wave-per-node: sqkv fp16 [N,768] (q|k|v).
// Block = 4 nodes; XCD-chunk remap for neighbor L2 locality.
// ---------------------------------------------------------------------------
__global__ __launch_bounds__(256) void attn_s(
    const f16* __restrict__ sqkv, const int* __restrict__ nbrs,
    const int* __restrict__ smask, f16* __restrict__ sctx, int G)
{
    __shared__ int nbL[4 * KK];
    __shared__ int mkL[4 * KK];
    const int tid = threadIdx.x;
    const int nbase = xcd_remap(blockIdx.x, G) * 4;
    if (tid < 4 * KK) {
        nbL[tid] = nbrs[nbase * KK + tid];
        mkL[tid] = smask[nbase * KK + tid];
    }
    __syncthreads();

    const int wv = tid >> 6, l = tid & 63;
    const int n = nbase + wv;
    const int col = ((l >> 3) * 32) + (l & 7) * 4;
    const float scale = 0.1767766952966369f;

    const f16x4 qv = *(const f16x4*)(sqkv + (size_t)n * 768 + col);
    const float q0 = (float)qv[0], q1 = (float)qv[1], q2 = (float)qv[2], q3 = (float)qv[3];

    float m = -3.0e38f, lsum = 0.f;
    float a0 = 0.f, a1 = 0.f, a2 = 0.f, a3 = 0.f;
    #pragma unroll
    for (int j = 0; j < KK; ++j) {
        const size_t row = (size_t)nbL[wv * KK + j] * 768;
        const f16x4 kk = *(const f16x4*)(sqkv + row + 256 + col);
        const f16x4 vv = *(const f16x4*)(sqkv + row + 512 + col);
        float p = q0 * (float)kk[0] + q1 * (float)kk[1]
                + q2 * (float)kk[2] + q3 * (float)kk[3];
        p += __shfl_xor(p, 1);
        p += __shfl_xor(p, 2);
        p += __shfl_xor(p, 4);
        const float s  = (mkL[wv * KK + j] == 0) ? NEGV : p * scale;
        const float mn = fmaxf(m, s);
        const float sc = exp2f((m - mn) * 1.44269504f);
        const float pe = exp2f((s - mn) * 1.44269504f);
        lsum = lsum * sc + pe;
        a0 = a0 * sc + pe * (float)vv[0];
        a1 = a1 * sc + pe * (float)vv[1];
        a2 = a2 * sc + pe * (float)vv[2];
        a3 = a3 * sc + pe * (float)vv[3];
        m = mn;
    }
    const float inv = 1.0f / lsum;
    f16x4 o;
    o[0] = (f16)(a0 * inv); o[1] = (f16)(a1 * inv);
    o[2] = (f16)(a2 * inv); o[3] = (f16)(a3 * inv);
    *(f16x4*)(sctx + (size_t)n * 256 + col) = o;
}

// ---------------------------------------------------------------------------
extern "C" void kernel_launch(void* const* d_in, const int* in_sizes, int n_in,
                              void* d_out, int out_size, void* d_ws, size_t ws_size,
                              hipStream_t stream)
{
    const float* x = (const float*)d_in[0];
    const int* nbrs  = (const int*)d_in[17];
    const int* tmask = (const int*)d_in[18];
    const int* smask = (const int*)d_in[19];
    float* out = (float*)d_out;

    const int N  = in_sizes[0] / (TT * 256);  // 10000
    const int MT = N * TT;                    // 50000

    // ---- workspace layout (~115 MB peak, no aliasing needed) ----
    f16* wth = (f16*)d_ws;                          // [2048][256]
    f16* wtl = wth + (size_t)2048 * 256;
    float* bc = (float*)(wtl + (size_t)2048 * 256); // [2048]
    f16* xh     = (f16*)(bc + 2048);                // [MT*256]
    f16* kvbuf  = xh + (size_t)MT * 256;            // [MT*512]
    f16* q16    = kvbuf + (size_t)MT * 512;         // [N*256]
    f16* ctx    = q16 + (size_t)N * 256;            // [N*256]
    f16* ht     = ctx + (size_t)N * 256;            // [N*256]
    f16* sqkv16 = ht + (size_t)N * 256;             // [N*768]
    f16* sctx   = sqkv16 + (size_t)N * 768;         // [N*256]

    // ---- weight prep: rows kv=[0,512) q=[512,768) ht=[768,1024)
    //      s(q,k,v)=[1024,1792) out=[1792,2048) ----
    PrepArgs pa;
    pa.W[0] = (const float*)d_in[3];  pa.b[0] = (const float*)d_in[4];   // tWk
    pa.W[1] = (const float*)d_in[5];  pa.b[1] = (const float*)d_in[6];   // tWv
    pa.W[2] = (const float*)d_in[1];  pa.b[2] = (const float*)d_in[2];   // tWq
    pa.W[3] = (const float*)d_in[7];  pa.b[3] = (const float*)d_in[8];   // tWo
    pa.W[4] = (const float*)d_in[9];  pa.b[4] = (const float*)d_in[10];  // sWq
    pa.W[5] = (const float*)d_in[11]; pa.b[5] = (const float*)d_in[12];  // sWk
    pa.W[6] = (const float*)d_in[13]; pa.b[6] = (const float*)d_in[14];  // sWv
    pa.W[7] = (const float*)d_in[15]; pa.b[7] = (const float*)d_in[16];  // sWo
    prep_w8<<<dim3(4, 4, 8), 256, 0, stream>>>(pa, wth, wtl, bc);

    // ---- x -> fp16 ----
    cvt_x<<<2048, 256, 0, stream>>>(x, xh, MT * 256 / 8);

    dim3 blk(512);
    const int GBM_T = (MT + 127) / 128;   // 391
    const int GBM_N = (N + 127) / 128;    // 79

    // kv projection: [MT x 512] -> fp16
    gemm_f16<1><<<GBM_T * 4, blk, 0, stream>>>(
        xh, 256, MT, wth, wtl, bc, nullptr, kvbuf, 512, 4, GBM_T * 4);
    // q projection (last timestep rows) -> fp16
    gemm_f16<1><<<GBM_N * 2, blk, 0, stream>>>(
        xh + (TT - 1) * 256, TT * 256, N,
        wth + (size_t)512 * 256, wtl + (size_t)512 * 256, bc + 512,
        nullptr, q16, 256, 2, GBM_N * 2);
    // temporal attention -> ctx fp16
    attn_t<<<N / 4, dim3(256), 0, stream>>>(q16, kvbuf, tmask, ctx);
    // h_t projection -> fp16
    gemm_f16<1><<<GBM_N * 2, blk, 0, stream>>>(
        ctx, 256, N,
        wth + (size_t)768 * 256, wtl + (size_t)768 * 256, bc + 768,
        nullptr, ht, 256, 2, GBM_N * 2);
    // fused spatial q/k/v projection: [N x 768] -> fp16
    gemm_f16<1><<<GBM_N * 6, blk, 0, stream>>>(
        ht, 256, N,
        wth + (size_t)1024 * 256, wtl + (size_t)1024 * 256, bc + 1024,
        nullptr, sqkv16, 768, 6, GBM_N * 6);
    // spatial attention -> sctx fp16 (XCD-chunked for neighbor L2 reuse)
    attn_s<<<N / 4, dim3(256), 0, stream>>>(sqkv16, nbrs, smask, sctx, N / 4);
    // output projection -> f32 out
    gemm_f16<0><<<GBM_N * 2, blk, 0, stream>>>(
        sctx, 256, N,
        wth + (size_t)1792 * 256, wtl + (size_t)1792 * 256, bc + 1792,
        out, nullptr, 256, 2, GBM_N * 2);
}

// Round 6
// 227.144 us; speedup vs baseline: 2.3510x; 1.1048x over previous
//
#include <hip/hip_runtime.h>

constexpr int TT = 5;     // temporal length
constexpr int KK = 25;    // spatial neighbors
#define NEGV -1e10f

typedef _Float16 f16;
typedef __attribute__((ext_vector_type(8))) _Float16 f16x8;
typedef __attribute__((ext_vector_type(4))) _Float16 f16x4;
typedef __attribute__((ext_vector_type(4))) float f32x4;

// async global -> LDS direct copy, 16 B/lane (wave-uniform LDS base + lane*16)
__device__ __forceinline__ void gload16(const void* g, void* l) {
    __builtin_amdgcn_global_load_lds(
        (const __attribute__((address_space(1))) unsigned int*)g,
        (__attribute__((address_space(3))) unsigned int*)l, 16, 0, 0);
}

// bijective XCD-chunk remap (m204)
__device__ __forceinline__ int xcd_remap(int id, int G) {
    const int c = id & 7, j = id >> 3;
    const int q = G >> 3, r = G & 7;
    const int base = (c < r) ? c * (q + 1) : r * (q + 1) + (c - r) * q;
    return base + j;
}

// ---------------------------------------------------------------------------
// Weight prep (ONE launch): W[z] [256k x 256n] f32 -> wt [z*256+n][k] fp16,
// biases concatenated f32. grid (4,4,8), block 256.
// ---------------------------------------------------------------------------
struct PrepArgs { const float* W[8]; const float* b[8]; };

__global__ __launch_bounds__(256) void prep_w8(
    PrepArgs pa, f16* __restrict__ wt, float* __restrict__ bc)
{
    __shared__ float sT[64][65];
    const int z = blockIdx.z;
    const float* W = pa.W[z];
    f16* wh = wt + (size_t)z * 65536;
    const int t  = threadIdx.x;
    const int k0 = blockIdx.x * 64, n0 = blockIdx.y * 64;
    const int kk = t >> 2;
    #pragma unroll
    for (int c = 0; c < 4; ++c) {
        const int col = (t & 3) * 16 + c * 4;
        float4 v = *(const float4*)(W + (size_t)(k0 + kk) * 256 + n0 + col);
        sT[kk][col] = v.x; sT[kk][col + 1] = v.y; sT[kk][col + 2] = v.z; sT[kk][col + 3] = v.w;
    }
    __syncthreads();
    const int n = t >> 2, ks = (t & 3) * 16;
    f16* ph = wh + (size_t)(n0 + n) * 256 + k0 + ks;
    #pragma unroll
    for (int j0 = 0; j0 < 16; j0 += 8) {
        f16x8 vh;
        #pragma unroll
        for (int j = 0; j < 8; ++j) vh[j] = (f16)sT[ks + j0 + j][n];
        *(f16x8*)(ph + j0) = vh;
    }
    if (blockIdx.x == 0 && blockIdx.y == 0) bc[z * 256 + t] = pa.b[z][t];
}

// ---------------------------------------------------------------------------
// x f32 -> fp16, 8 elems/thread (16B stores).
// ---------------------------------------------------------------------------
__global__ __launch_bounds__(256) void cvt_x(
    const float* __restrict__ x, f16* __restrict__ xh, int n8)
{
    for (int i = blockIdx.x * 256 + threadIdx.x; i < n8; i += gridDim.x * 256) {
        const float4 a = ((const float4*)x)[2 * i];
        const float4 b = ((const float4*)x)[2 * i + 1];
        f16x8 o;
        o[0] = (f16)a.x; o[1] = (f16)a.y; o[2] = (f16)a.z; o[3] = (f16)a.w;
        o[4] = (f16)b.x; o[5] = (f16)b.y; o[6] = (f16)b.z; o[7] = (f16)b.w;
        *(f16x8*)(xh + (size_t)i * 8) = o;
    }
}

// ---------------------------------------------------------------------------
// fp16 MFMA GEMM, 2-phase prefetch: C[M x Ntot] = A_f16 @ W^T + bias.
// Tile BM x 128, BK=64, double-buffered LDS, 1 barrier/K-step, XOR swizzle
// (linear LDS dest + inverse-swizzled global source + swizzled ds_read).
// 512 thr = 8 waves (2 wm x 4 wn), per-wave (BM/2) x 32 out.
// OM: 0 = f32 out, 1 = fp16 out.
// ---------------------------------------------------------------------------
template<int BM, int OM>
__global__ __launch_bounds__(512, 4) void gemm_f16(
    const f16* __restrict__ A, int lda, int M,
    const f16* __restrict__ W, const float* __restrict__ bias,
    float* __restrict__ Cf, f16* __restrict__ Ch, int ldc,
    int GY, int G)
{
    constexpr int MF   = BM / 32;   // 16-row frags per wave
    constexpr int ASEG = BM / 64;   // A gload16 wave-instr per k-step
    __shared__ f16 sA[2][BM * 64];
    __shared__ f16 sB[2][128 * 64];

    const int tid = threadIdx.x;
    const int l   = tid & 63, w = tid >> 6;
    const int l15 = l & 15, l4 = l >> 4;
    const int wm  = w >> 2, wn = w & 3;

    const int p  = xcd_remap(blockIdx.x, G);
    const int bm = (p / GY) * BM;
    const int bn = (p % GY) * 128;

    // staging source (inverse-swizzled col-group so swizzled reads see linear data)
    const int srow8 = l >> 3;                        // row-in-8-group
    const int scol  = ((l & 7) ^ srow8) * 8;         // f16 col offset, 16B units
    size_t aoff[ASEG];
    #pragma unroll
    for (int j = 0; j < ASEG; ++j) {
        int r = bm + (w * ASEG + j) * 8 + srow8;
        if (r > M - 1) r = M - 1;                    // clamp reads; stores guarded
        aoff[j] = (size_t)r * lda + scol;
    }
    size_t boff[2];
    #pragma unroll
    for (int j = 0; j < 2; ++j)
        boff[j] = (size_t)(bn + (w * 2 + j) * 8 + srow8) * 256 + scol;

    f32x4 acc[MF][2];
    #pragma unroll
    for (int i = 0; i < MF; ++i)
        #pragma unroll
        for (int j = 0; j < 2; ++j) acc[i][j] = f32x4{0.f, 0.f, 0.f, 0.f};

    auto STAGE = [&](int buf, int k0) {
        #pragma unroll
        for (int j = 0; j < ASEG; ++j)
            gload16(A + aoff[j] + k0, &sA[buf][(w * ASEG + j) * 512]);
        #pragma unroll
        for (int j = 0; j < 2; ++j)
            gload16(W + boff[j] + k0, &sB[buf][(w * 2 + j) * 512]);
    };

    STAGE(0, 0);
    __syncthreads();                 // drains vmcnt -> buf0 valid

    const int swz = l15 & 7;         // read-side row-XOR
    #pragma unroll
    for (int t = 0; t < 4; ++t) {
        if (t < 3) STAGE((t + 1) & 1, (t + 1) * 64);   // prefetch next K-slice

        f16x8 af[MF][2], bf[2][2];
        #pragma unroll
        for (int mf = 0; mf < MF; ++mf) {
            const int r = wm * (BM / 2) + mf * 16 + l15;
            #pragma unroll
            for (int ks = 0; ks < 2; ++ks)
                af[mf][ks] = *(const f16x8*)&sA[t & 1][r * 64 + (((ks * 4 + l4) ^ swz) * 8)];
        }
        #pragma unroll
        for (int nf = 0; nf < 2; ++nf) {
            const int r = wn * 32 + nf * 16 + l15;
            #pragma unroll
            for (int ks = 0; ks < 2; ++ks)
                bf[nf][ks] = *(const f16x8*)&sB[t & 1][r * 64 + (((ks * 4 + l4) ^ swz) * 8)];
        }
        #pragma unroll
        for (int mf = 0; mf < MF; ++mf)
            #pragma unroll
            for (int nf = 0; nf < 2; ++nf)
                #pragma unroll
                for (int ks = 0; ks < 2; ++ks)
                    acc[mf][nf] = __builtin_amdgcn_mfma_f32_16x16x32_f16(
                        af[mf][ks], bf[nf][ks], acc[mf][nf], 0, 0, 0);
        __syncthreads();             // stage done (vmcnt0) + reads done -> swap safe
    }

    // epilogue: bias + store
    #pragma unroll
    for (int mf = 0; mf < MF; ++mf) {
        const int row0 = bm + wm * (BM / 2) + mf * 16 + l4 * 4;
        #pragma unroll
        for (int nf = 0; nf < 2; ++nf) {
            const int col = bn + wn * 32 + nf * 16 + l15;
            const float bs = bias[col];
            #pragma unroll
            for (int i = 0; i < 4; ++i) {
                const int row = row0 + i;
                if (row < M) {
                    const float v = acc[mf][nf][i] + bs;
                    const size_t o = (size_t)row * ldc + col;
                    if (OM == 0) Cf[o] = v;
                    else         Ch[o] = (f16)v;
                }
            }
        }
    }
}

// ---------------------------------------------------------------------------
// Temporal attention, wave-per-node: lane = (h, dq), 4 d-elems per lane.
// ---------------------------------------------------------------------------
__global__ __launch_bounds__(256) void attn_t(
    const f16* __restrict__ q, const f16* __restrict__ kv,
    const int* __restrict__ tmask, f16* __restrict__ ctx)
{
    const int tid = threadIdx.x;
    const int wv = tid >> 6, l = tid & 63;
    const int n = blockIdx.x * 4 + wv;
    const int col = ((l >> 3) * 32) + (l & 7) * 4;   // h*32 + dq*4
    const float scale = 0.1767766952966369f;

    const f16x4 qv = *(const f16x4*)(q + (size_t)n * 256 + col);
    const float q0 = (float)qv[0], q1 = (float)qv[1], q2 = (float)qv[2], q3 = (float)qv[3];

    float m = -3.0e38f, lsum = 0.f;
    float a0 = 0.f, a1 = 0.f, a2 = 0.f, a3 = 0.f;
    #pragma unroll
    for (int t = 0; t < TT; ++t) {
        const size_t row = ((size_t)n * TT + t) * 512;
        const f16x4 kk = *(const f16x4*)(kv + row + col);
        const f16x4 vv = *(const f16x4*)(kv + row + 256 + col);
        float p = q0 * (float)kk[0] + q1 * (float)kk[1]
                + q2 * (float)kk[2] + q3 * (float)kk[3];
        p += __shfl_xor(p, 1);
        p += __shfl_xor(p, 2);
        p += __shfl_xor(p, 4);
        const float s  = (tmask[n * TT + t] == 0) ? NEGV : p * scale;
        const float mn = fmaxf(m, s);
        const float sc = exp2f((m - mn) * 1.44269504f);
        const float pe = exp2f((s - mn) * 1.44269504f);
        lsum = lsum * sc + pe;
        a0 = a0 * sc + pe * (float)vv[0];
        a1 = a1 * sc + pe * (float)vv[1];
        a2 = a2 * sc + pe * (float)vv[2];
        a3 = a3 * sc + pe * (float)vv[3];
        m = mn;
    }
    const float inv = 1.0f / lsum;
    f16x4 o;
    o[0] = (f16)(a0 * inv); o[1] = (f16)(a1 * inv);
    o[2] = (f16)(a2 * inv); o[3] = (f16)(a3 * inv);
    *(f16x4*)(ctx + (size_t)n * 256 + col) = o;
}

// ---------------------------------------------------------------------------
// Spatial attention, wave-per-node; XCD-chunk remap for neighbor L2 locality.
// ---------------------------------------------------------------------------
__global__ __launch_bounds__(256) void attn_s(
    const f16* __restrict__ sqkv, const int* __restrict__ nbrs,
    const int* __restrict__ smask, f16* __restrict__ sctx, int G)
{
    __shared__ int nbL[4 * KK];
    __shared__ int mkL[4 * KK];
    const int tid = threadIdx.x;
    const int nbase = xcd_remap(blockIdx.x, G) * 4;
    if (tid < 4 * KK) {
        nbL[tid] = nbrs[nbase * KK + tid];
        mkL[tid] = smask[nbase * KK + tid];
    }
    __syncthreads();

    const int wv = tid >> 6, l = tid & 63;
    const int n = nbase + wv;
    const int col = ((l >> 3) * 32) + (l & 7) * 4;
    const float scale = 0.1767766952966369f;

    const f16x4 qv = *(const f16x4*)(sqkv + (size_t)n * 768 + col);
    const float q0 = (float)qv[0], q1 = (float)qv[1], q2 = (float)qv[2], q3 = (float)qv[3];

    float m = -3.0e38f, lsum = 0.f;
    float a0 = 0.f, a1 = 0.f, a2 = 0.f, a3 = 0.f;
    #pragma unroll
    for (int j = 0; j < KK; ++j) {
        const size_t row = (size_t)nbL[wv * KK + j] * 768;
        const f16x4 kk = *(const f16x4*)(sqkv + row + 256 + col);
        const f16x4 vv = *(const f16x4*)(sqkv + row + 512 + col);
        float p = q0 * (float)kk[0] + q1 * (float)kk[1]
                + q2 * (float)kk[2] + q3 * (float)kk[3];
        p += __shfl_xor(p, 1);
        p += __shfl_xor(p, 2);
        p += __shfl_xor(p, 4);
        const float s  = (mkL[wv * KK + j] == 0) ? NEGV : p * scale;
        const float mn = fmaxf(m, s);
        const float sc = exp2f((m - mn) * 1.44269504f);
        const float pe = exp2f((s - mn) * 1.44269504f);
        lsum = lsum * sc + pe;
        a0 = a0 * sc + pe * (float)vv[0];
        a1 = a1 * sc + pe * (float)vv[1];
        a2 = a2 * sc + pe * (float)vv[2];
        a3 = a3 * sc + pe * (float)vv[3];
        m = mn;
    }
    const float inv = 1.0f / lsum;
    f16x4 o;
    o[0] = (f16)(a0 * inv); o[1] = (f16)(a1 * inv);
    o[2] = (f16)(a2 * inv); o[3] = (f16)(a3 * inv);
    *(f16x4*)(sctx + (size_t)n * 256 + col) = o;
}

// ---------------------------------------------------------------------------
extern "C" void kernel_launch(void* const* d_in, const int* in_sizes, int n_in,
                              void* d_out, int out_size, void* d_ws, size_t ws_size,
                              hipStream_t stream)
{
    const float* x = (const float*)d_in[0];
    const int* nbrs  = (const int*)d_in[17];
    const int* tmask = (const int*)d_in[18];
    const int* smask = (const int*)d_in[19];
    float* out = (float*)d_out;

    const int N  = in_sizes[0] / (TT * 256);  // 10000
    const int MT = N * TT;                    // 50000

    // ---- workspace layout (~113 MB peak) ----
    f16* wt  = (f16*)d_ws;                          // [2048][256]
    float* bc = (float*)(wt + (size_t)2048 * 256);  // [2048]
    f16* xh     = (f16*)(bc + 2048);                // [MT*256]
    f16* kvbuf  = xh + (size_t)MT * 256;            // [MT*512]
    f16* q16    = kvbuf + (size_t)MT * 512;         // [N*256]
    f16* ctx    = q16 + (size_t)N * 256;            // [N*256]
    f16* ht     = ctx + (size_t)N * 256;            // [N*256]
    f16* sqkv16 = ht + (size_t)N * 256;             // [N*768]
    f16* sctx   = sqkv16 + (size_t)N * 768;         // [N*256]

    // weight rows: kv=[0,512) q=[512,768) ht=[768,1024) s=[1024,1792) out=[1792,2048)
    PrepArgs pa;
    pa.W[0] = (const float*)d_in[3];  pa.b[0] = (const float*)d_in[4];   // tWk
    pa.W[1] = (const float*)d_in[5];  pa.b[1] = (const float*)d_in[6];   // tWv
    pa.W[2] = (const float*)d_in[1];  pa.b[2] = (const float*)d_in[2];   // tWq
    pa.W[3] = (const float*)d_in[7];  pa.b[3] = (const float*)d_in[8];   // tWo
    pa.W[4] = (const float*)d_in[9];  pa.b[4] = (const float*)d_in[10];  // sWq
    pa.W[5] = (const float*)d_in[11]; pa.b[5] = (const float*)d_in[12];  // sWk
    pa.W[6] = (const float*)d_in[13]; pa.b[6] = (const float*)d_in[14];  // sWv
    pa.W[7] = (const float*)d_in[15]; pa.b[7] = (const float*)d_in[16];  // sWo
    prep_w8<<<dim3(4, 4, 8), 256, 0, stream>>>(pa, wt, bc);

    cvt_x<<<2048, 256, 0, stream>>>(x, xh, MT * 256 / 8);

    dim3 blk(512);
    const int GBM_T = (MT + 127) / 128;   // 391
    const int GBM_S = (N + 63) / 64;      // 157

    // kv projection: [MT x 512] -> fp16
    gemm_f16<128, 1><<<GBM_T * 4, blk, 0, stream>>>(
        xh, 256, MT, wt, bc, nullptr, kvbuf, 512, 4, GBM_T * 4);
    // q projection (last timestep rows) -> fp16
    gemm_f16<64, 1><<<GBM_S * 2, blk, 0, stream>>>(
        xh + (TT - 1) * 256, TT * 256, N,
        wt + (size_t)512 * 256, bc + 512, nullptr, q16, 256, 2, GBM_S * 2);
    // temporal attention -> ctx fp16
    attn_t<<<N / 4, dim3(256), 0, stream>>>(q16, kvbuf, tmask, ctx);
    // h_t projection -> fp16
    gemm_f16<64, 1><<<GBM_S * 2, blk, 0, stream>>>(
        ctx, 256, N, wt + (size_t)768 * 256, bc + 768,
        nullptr, ht, 256, 2, GBM_S * 2);
    // fused spatial q/k/v projection: [N x 768] -> fp16
    gemm_f16<64, 1><<<GBM_S * 6, blk, 0, stream>>>(
        ht, 256, N, wt + (size_t)1024 * 256, bc + 1024,
        nullptr, sqkv16, 768, 6, GBM_S * 6);
    // spatial attention -> sctx fp16 (XCD-chunked)
    attn_s<<<N / 4, dim3(256), 0, stream>>>(sqkv16, nbrs, smask, sctx, N / 4);
    // output projection -> f32 out
    gemm_f16<64, 0><<<GBM_S * 2, blk, 0, stream>>>(
        sctx, 256, N, wt + (size_t)1792 * 256, bc + 1792,
        out, nullptr, 256, 2, GBM_S * 2);
}